// Round 4
// baseline (512.151 us; speedup 1.0000x reference)
//
#include <hip/hip_runtime.h>
#include <hip/hip_fp16.h>

#define MM 8192
#define NN 4096
#define KK 4096
#define BM 256
#define BN 256
#define BK 64
#define NT (KK / BK)   // 64 K-tiles

typedef __attribute__((ext_vector_type(8))) short bf16x8;
typedef __attribute__((ext_vector_type(16))) float floatx16;
typedef __attribute__((ext_vector_type(8))) unsigned short ushort8_t;

typedef const __attribute__((address_space(1))) unsigned int* gptr_t;
typedef __attribute__((address_space(3))) unsigned int* lptr_t;

// round-to-nearest-even fp32 -> bf16 bits (valid for non-NaN inputs)
__device__ __forceinline__ unsigned short f2bf(float f) {
    unsigned u = __builtin_bit_cast(unsigned, f);
    u += 0x7FFFu + ((u >> 16) & 1u);
    return (unsigned short)(u >> 16);
}

__device__ __forceinline__ unsigned short sign_bf16(float f) {
    // sign(clip(fp16(f),-1,1)) == sign(fp16(f)); fp16 rounds |f|<2^-25 to 0
    float h = __half2float(__float2half(f));
    return (h > 0.f) ? 0x3F80u : ((h < 0.f) ? 0xBF80u : 0u);
}

// ---- Prepass 1: x fp32 -> bf16. Two fully-contiguous streams per block ----
__global__ __launch_bounds__(256) void cvt_x_kernel(const float4* __restrict__ x4,
                                                    ushort4* __restrict__ o4) {
    int i0 = blockIdx.x * 512 + threadIdx.x;
    int i1 = i0 + 256;
    float4 a = x4[i0];
    float4 b = x4[i1];
    ushort4 oa, ob;
    oa.x = f2bf(a.x); oa.y = f2bf(a.y); oa.z = f2bf(a.z); oa.w = f2bf(a.w);
    ob.x = f2bf(b.x); ob.y = f2bf(b.y); ob.z = f2bf(b.z); ob.w = f2bf(b.w);
    o4[i0] = oa;
    o4[i1] = ob;
}

// ---- Prepass 2: w (K x N fp32) -> sign(fp16(w)) bf16, transposed to N x K ----
__global__ __launch_bounds__(256) void binz_wt_kernel(const float* __restrict__ w,
                                                      unsigned short* __restrict__ wt) {
    __shared__ unsigned short tileT[64][72];   // [n][k]; 144B row stride
    const int n0 = blockIdx.x * 64;
    const int k0 = blockIdx.y * 64;
    const int t  = threadIdx.x;
    {
        const int c4 = t & 15;
        const int rb = t >> 4;
#pragma unroll
        for (int i = 0; i < 4; ++i) {
            int r = rb + i * 16;
            float4 v = *(const float4*)&w[(size_t)(k0 + r) * NN + n0 + c4 * 4];
            tileT[c4 * 4 + 0][r] = sign_bf16(v.x);
            tileT[c4 * 4 + 1][r] = sign_bf16(v.y);
            tileT[c4 * 4 + 2][r] = sign_bf16(v.z);
            tileT[c4 * 4 + 3][r] = sign_bf16(v.w);
        }
    }
    __syncthreads();
    {
        const int g  = t & 7;
        const int nb = t >> 3;
#pragma unroll
        for (int i = 0; i < 2; ++i) {
            int n = nb + i * 32;
            *(ushort8_t*)&wt[(size_t)(n0 + n) * KK + k0 + g * 8] =
                *(const ushort8_t*)&tileT[n][g * 8];
        }
    }
}

// ---- GEMM: 256x256, BK=64, 8 waves, 4-phase/K-tile, 32x32x16 MFMA ----
// LDS: A slots [buf][half] 16 KiB @0..64K, B same @64K..128K. 16B-chunk XOR swizzle
// (lds(row,cg) = global(row, cg^(row&7)); read chunk c at lds cg = c^(row&7)).
// Fragments (32x32x16, HW-verified round-0/m74/m101): A row = l&31, k=(l>>5)*8+e;
// C/D col = l&31, row = (r&3)+8*(r>>2)+4*(l>>5).
// Wave tile 128x64: af[mf=4][kf=4], bf[nf=2][kf=4], acc[4][2] floatx16.
// Phases (8 MFMA each): p0 mf01xnf0, p1 mf23xnf0, p2 mf01xnf1, p3 mf23xnf1.
// Reads: p0 af[0,1]+bf[0] (12); p1 af[2,3] (8); p2 bf[1] (4); p3 none.
// Stages: p0 A1(t+1); p3 B1(t+2)+A0(t+2)+B0(t+2). vmcnt(6) at p3 end
// (vmcnt(0) at t==NT-2).
// WAR (NB: each wave reads its OWN half at BOTH p0 and p2 -- B0 and B1 are both
// live until p2's lgkmcnt(0); this is why ALL B stages sit at p3, after p2's
// barrier; round-2's B0-stage-at-p1 raced wn01-waves' bf[1] reads at p2):
//   B0(t)/B1(t): last reads p2, drained p2 lgkm0+barrier < p3 stages.  A0(t):
//   last reads p1, drained p1 < p3 stage.  A1(t-1): drained t-1 p1 < t p0 stage
//   (opposite-parity slot from tile t's reads).
// RAW: entering p3: 6 {B1,A0,B0}(t+1) + 2 A1(t+1) + 6 (t+2) = 14 in flight;
//   vmcnt(6) completes the 8 = tile t+1 exactly. Prologue seeds the same set.
__global__ __launch_bounds__(512, 2) void gemm_bin_kernel(const unsigned short* __restrict__ A,
                                                          const unsigned short* __restrict__ Bt,
                                                          float* __restrict__ C) {
    __shared__ __align__(16) char lds[131072];

    const int tid    = threadIdx.x;
    const int lane   = tid & 63;
    const int wave   = tid >> 6;                       // 0..7
    const int wave_u = __builtin_amdgcn_readfirstlane(wave);
    const int wm     = wave >> 2;                      // 0..1  (128 M-rows each)
    const int wn     = wave & 3;                       // 0..3  (64 N-cols each)
    const int l31    = lane & 31;
    const int kh     = lane >> 5;                      // k-half within K=16

    // XCD-bijective swizzle: 512 wgs, 8 XCDs, 64 contiguous per XCD
    const int bid = blockIdx.x;
    const int wg  = (bid & 7) * 64 + (bid >> 3);
    const int bn0 = (wg & 15) * BN;
    const int bm0 = (wg >> 4) * BM;

    // staging: chunk = tid; row = tid>>3, cg = tid&7; inverse-swizzled source col
    const int r0 = tid >> 3;                           // 0..63
    const int c0 = (tid & 7) ^ (r0 & 7);
    const char* gA = (const char*)A;
    const char* gB = (const char*)Bt;
    const size_t aoff = (size_t)(bm0 + r0) * (KK * 2) + (size_t)c0 * 16;
    const size_t boff = (size_t)(bn0 + r0) * (KK * 2) + (size_t)c0 * 16;

    __attribute__((address_space(3))) char* lds3 =
        (__attribute__((address_space(3))) char*)lds;
    const int dstw = wave_u * 1024;

    // frag read chunk offsets: chunk (kf*2+kh) ^ (row&7), row&7 == lane&7
    const int aco0 = ((0 * 2 + kh) ^ (lane & 7)) * 16;
    const int aco1 = ((1 * 2 + kh) ^ (lane & 7)) * 16;
    const int aco2 = ((2 * 2 + kh) ^ (lane & 7)) * 16;
    const int aco3 = ((3 * 2 + kh) ^ (lane & 7)) * 16;
    const char* ldsA_l = lds + l31 * 128;                              // + slot*16K + mf*4096
    const char* ldsB_l = lds + 65536 + ((wn & 1) * 64 + l31) * 128;    // + slot*16K + nf*4096
    const char* pA0 = ldsA_l + (0 * 2 + wm) * 16384;
    const char* pA1 = ldsA_l + (1 * 2 + wm) * 16384;
    const char* pB0 = ldsB_l + (0 * 2 + (wn >> 1)) * 16384;
    const char* pB1 = ldsB_l + (1 * 2 + (wn >> 1)) * 16384;

    floatx16 acc[4][2] = {};
    bf16x8 af[4][4];
    bf16x8 bf[2][4];

    auto STAGE_A = [&](int h, int kt) {
        const int slot = (kt & 1) * 2 + h;
        const char* s0 = gA + aoff + (size_t)h * (128 * KK * 2) + (size_t)kt * (BK * 2);
        __builtin_amdgcn_global_load_lds((gptr_t)s0,
            (lptr_t)(lds3 + slot * 16384 + dstw), 16, 0, 0);
        __builtin_amdgcn_global_load_lds((gptr_t)(s0 + (size_t)64 * KK * 2),
            (lptr_t)(lds3 + slot * 16384 + 8192 + dstw), 16, 0, 0);
    };
    auto STAGE_B = [&](int h, int kt) {
        const int slot = (kt & 1) * 2 + h;
        const char* s0 = gB + boff + (size_t)h * (128 * KK * 2) + (size_t)kt * (BK * 2);
        __builtin_amdgcn_global_load_lds((gptr_t)s0,
            (lptr_t)(lds3 + 65536 + slot * 16384 + dstw), 16, 0, 0);
        __builtin_amdgcn_global_load_lds((gptr_t)(s0 + (size_t)64 * KK * 2),
            (lptr_t)(lds3 + 65536 + slot * 16384 + 8192 + dstw), 16, 0, 0);
    };
    auto LDA = [&](const char* pAp, int mf) {
        af[mf][0] = *(const bf16x8*)(pAp + mf * 4096 + aco0);
        af[mf][1] = *(const bf16x8*)(pAp + mf * 4096 + aco1);
        af[mf][2] = *(const bf16x8*)(pAp + mf * 4096 + aco2);
        af[mf][3] = *(const bf16x8*)(pAp + mf * 4096 + aco3);
    };
    auto LDB = [&](const char* pBp, int nf) {
        bf[nf][0] = *(const bf16x8*)(pBp + nf * 4096 + aco0);
        bf[nf][1] = *(const bf16x8*)(pBp + nf * 4096 + aco1);
        bf[nf][2] = *(const bf16x8*)(pBp + nf * 4096 + aco2);
        bf[nf][3] = *(const bf16x8*)(pBp + nf * 4096 + aco3);
    };
    auto MFMA8 = [&](int mh, int nf) {   // 2 mf x 4 kf = 8 MFMA (32x32x16)
#pragma unroll
        for (int mi = 0; mi < 2; ++mi)
#pragma unroll
            for (int kf = 0; kf < 4; ++kf)
                acc[2 * mh + mi][nf] = __builtin_amdgcn_mfma_f32_32x32x16_bf16(
                    af[2 * mh + mi][kf], bf[nf][kf], acc[2 * mh + mi][nf], 0, 0, 0);
    };

#define WAITL0 do { asm volatile("s_waitcnt lgkmcnt(0)" ::: "memory"); \
                    __builtin_amdgcn_sched_barrier(0); } while (0)

    // ---- prologue: stage tile0 (4 halves) + tile1 (B1,A0,B0); wait tile0 ----
    STAGE_B(0, 0); STAGE_B(1, 0); STAGE_A(0, 0); STAGE_A(1, 0);
    STAGE_B(1, 1); STAGE_A(0, 1); STAGE_B(0, 1);
    asm volatile("s_waitcnt vmcnt(6)" ::: "memory");
    __builtin_amdgcn_s_barrier();

#define TILE_BODY(t, pAc, pBc)                                                  \
    {                                                                           \
        /* ph0: read af[0,1]+bf[0]; stage A1(t+1); mf01 x nf0 */                \
        LDA(pAc, 0); LDA(pAc, 1); LDB(pBc, 0);                                  \
        if ((t) + 1 < NT) STAGE_A(1, (t) + 1);                                  \
        __builtin_amdgcn_s_barrier();                                           \
        WAITL0;                                                                 \
        __builtin_amdgcn_s_setprio(1);                                          \
        MFMA8(0, 0);                                                            \
        __builtin_amdgcn_s_setprio(0);                                          \
        __builtin_amdgcn_s_barrier();                                           \
        /* ph1: read af[2,3]; mf23 x nf0 */                                     \
        LDA(pAc, 2); LDA(pAc, 3);                                               \
        __builtin_amdgcn_s_barrier();                                           \
        WAITL0;                                                                 \
        __builtin_amdgcn_s_setprio(1);                                          \
        MFMA8(1, 0);                                                            \
        __builtin_amdgcn_s_setprio(0);                                          \
        __builtin_amdgcn_s_barrier();                                           \
        /* ph2: read bf[1]; mf01 x nf1 */                                       \
        LDB(pBc, 1);                                                            \
        __builtin_amdgcn_s_barrier();                                           \
        WAITL0;                                                                 \
        __builtin_amdgcn_s_setprio(1);                                          \
        MFMA8(0, 1);                                                            \
        __builtin_amdgcn_s_setprio(0);                                          \
        __builtin_amdgcn_s_barrier();                                           \
        /* ph3: stage B1,A0,B0(t+2) (all B reads drained at p2); mf23 x nf1 */  \
        if ((t) + 2 < NT) { STAGE_B(1, (t) + 2); STAGE_A(0, (t) + 2);           \
                            STAGE_B(0, (t) + 2); }                              \
        __builtin_amdgcn_s_setprio(1);                                          \
        MFMA8(1, 1);                                                            \
        __builtin_amdgcn_s_setprio(0);                                          \
        if ((t) == NT - 2) { asm volatile("s_waitcnt vmcnt(0)" ::: "memory"); } \
        else               { asm volatile("s_waitcnt vmcnt(6)" ::: "memory"); } \
        __builtin_amdgcn_s_barrier();                                           \
    }

    for (int tb = 0; tb < NT; tb += 2) {
        TILE_BODY(tb,     pA0, pB0);
        TILE_BODY(tb + 1, pA1, pB1);
    }
#undef TILE_BODY
#undef WAITL0

    // ---- epilogue: 32x32 C/D layout col=lane&31, row=(r&3)+8*(r>>2)+4*(lane>>5)
    // [HW-verified m74/m101; identical to round-0's passing epilogue] ----
#pragma unroll
    for (int mf = 0; mf < 4; ++mf) {
#pragma unroll
        for (int nf = 0; nf < 2; ++nf) {
            const int rbase = bm0 + wm * 128 + mf * 32 + 4 * kh;
            const int col   = bn0 + wn * 64 + nf * 32 + l31;
#pragma unroll
            for (int r = 0; r < 16; ++r) {
                int row = rbase + (r & 3) + 8 * (r >> 2);
                C[(size_t)row * NN + col] = acc[mf][nf][r];
            }
        }
    }
}

// ---- Fallback (insurance if ws too small): correct but slow ----
__global__ __launch_bounds__(256) void fallback_kernel(const float* __restrict__ x,
                                                       const float* __restrict__ w,
                                                       float* __restrict__ out) {
    int n = blockIdx.x * 256 + threadIdx.x;
    int m = blockIdx.y;
    float s = 0.f;
    for (int k = 0; k < KK; ++k) {
        float h = __half2float(__float2half(w[(size_t)k * NN + n]));
        float b = (h > 0.f) ? 1.f : ((h < 0.f) ? -1.f : 0.f);
        s += x[(size_t)m * KK + k] * b;
    }
    out[(size_t)m * NN + n] = s;
}

extern "C" void kernel_launch(void* const* d_in, const int* in_sizes, int n_in,
                              void* d_out, int out_size, void* d_ws, size_t ws_size,
                              hipStream_t stream) {
    const float* x = (const float*)d_in[0];
    const float* w = (const float*)d_in[1];
    if (n_in >= 2 && in_sizes[0] != MM * KK) {
        x = (const float*)d_in[1];
        w = (const float*)d_in[0];
    }
    float* out = (float*)d_out;

    const size_t xb_bytes = (size_t)MM * KK * 2;   // 64 MiB
    const size_t wt_bytes = (size_t)NN * KK * 2;   // 32 MiB

    if (ws_size >= xb_bytes + wt_bytes) {
        unsigned short* xb = (unsigned short*)d_ws;
        unsigned short* wt = (unsigned short*)((char*)d_ws + xb_bytes);

        int nblk = MM * KK / 4 / 512;   // two float4 per thread
        cvt_x_kernel<<<nblk, 256, 0, stream>>>((const float4*)x, (ushort4*)xb);
        binz_wt_kernel<<<dim3(NN / 64, KK / 64), 256, 0, stream>>>(w, wt);
        gemm_bin_kernel<<<dim3((NN / BN) * (MM / BM)), dim3(512), 0, stream>>>(xb, wt, out);
    } else {
        fallback_kernel<<<dim3(NN / 256, MM), 256, 0, stream>>>(x, w, out);
    }
}